// Round 5
// baseline (46.188 us; speedup 1.0000x reference)
//
#include <hip/hip_runtime.h>

#define DISP_RANGE 10
#define OUT_D 21
#define B_ 8
#define A_ 9
#define D_ 128
#define HW_ 4096   // 64*64
#define NT 4       // b-tiles chained per block

// cost[b,0,a,k,h,w] = wt_k * sum_{dd in [START0+s_k, START0+e_k)} uh[b,a, dd-32+h, h, w]  (0 if row OOB)
// cost[b,1,a,k,h,w] = wt_k * sum_{dd in [START0+s_k, START0+e_k)} vw[b,a, dd-32+w, h, w]  (0 if row OOB)
//
// Persistent 4-tile pipeline per block (T14 async-STAGE split):
//   step i: sync; issue global loads for tile i+1 -> regs; compute tile i
//           (uh direct-global + vw from LDS buf[i&1]); ds_write regs -> buf[(i+1)&1].
// HBM latency of stage(i+1) hides under compute(i). Reg-staging (not
// global_load_lds) keeps the compiler from inserting conservative vmcnt drains
// before the LDS reads. Diagonal vw read in LDS is stride-65 words -> conflict-free.
// AD = max(|a-4|,1) and wave id are template params: all window bounds constexpr.

template<int AD> struct G {
    static constexpr int L      = 2 * DISP_RANGE * AD + 1;
    static constexpr int START0 = 64 - DISP_RANGE * AD;
    static constexpr int LO     = (START0 - 32 < 0) ? 0 : (START0 - 32);
    static constexpr int HI     = (START0 + L + 31 > D_) ? D_ : (START0 + L + 31);
    static constexpr int NROWS  = HI - LO;     // 84 / 104 / 124 / 128
    static constexpr int NCH    = NROWS / 4;   // 1KB chunks (4 rows x 64 floats)
};

// k-groups across 8 waves: sizes {3,3,3,3,3,2,2,2}
template<int WID> struct KG {
    static constexpr int K0 = (WID < 5) ? 3 * WID : 15 + 2 * (WID - 5);
    static constexpr int NK = (WID < 5) ? 3 : 2;
    static constexpr int K1 = K0 + NK;
};

// chunks this wave stages: c = WID, WID+8, ...
template<int AD, int WID> struct ST {
    static constexpr int K = (G<AD>::NCH - WID + 7) / 8;
};

template<int AD, int WID>
__device__ __forceinline__ void stage_load(const float* __restrict__ vw_slice,
                                           float4* r, int lane) {
#pragma unroll
    for (int j = 0; j < ST<AD, WID>::K; ++j) {
        const int c = WID + 8 * j;
        r[j] = *reinterpret_cast<const float4*>(
            vw_slice + (size_t)(G<AD>::LO + c * 4 + (lane >> 4)) * HW_
                     + (size_t)((lane & 15) * 4));
    }
}

template<int AD, int WID>
__device__ __forceinline__ void stage_write(float* buf, const float4* r, int lane) {
#pragma unroll
    for (int j = 0; j < ST<AD, WID>::K; ++j) {
        const int c = WID + 8 * j;
        *reinterpret_cast<float4*>(&buf[c * 256 + (lane >> 4) * 64 + (lane & 15) * 4]) = r[j];
    }
}

template<int AD, int WID>
__device__ __forceinline__ void compute_tile(
    const float* __restrict__ uh_slice,   // uh + plane + h*64
    const float* buf,                     // staged vw rows [LO,HI)
    float* __restrict__ out0,             // out + base(n=0) + w
    float* __restrict__ out1,             // out + base(n=1) + w
    int h, int w)
{
    using g = G<AD>; using kg = KG<WID>;
    constexpr int S0 = (kg::K0 * g::L) / OUT_D;
    constexpr int E1 = (kg::K1 * g::L + OUT_D - 1) / OUT_D;

    float acc0[kg::NK];
    float acc1[kg::NK];
#pragma unroll
    for (int i = 0; i < kg::NK; ++i) { acc0[i] = 0.0f; acc1[i] = 0.0f; }

#pragma unroll
    for (int dd = g::START0 + S0; dd < g::START0 + E1; ++dd) {
        const int  row  = dd - 32 + h;
        const bool ok0  = (row >= 0) && (row < D_);
        const int  rowc = row < 0 ? 0 : (row > D_ - 1 ? D_ - 1 : row);
        float v0 = uh_slice[(size_t)rowc * HW_ + (size_t)w];
        v0 = ok0 ? v0 : 0.0f;

        const int  rv  = dd - 32 + w;
        const bool ok1 = (rv >= g::LO) && (rv < g::HI);
        const int  rvc = rv < g::LO ? g::LO : (rv > g::HI - 1 ? g::HI - 1 : rv);
        float v1 = buf[(rvc - g::LO) * 64 + w];
        v1 = ok1 ? v1 : 0.0f;

#pragma unroll
        for (int k = kg::K0; k < kg::K1; ++k) {
            if (dd >= g::START0 + (k * g::L) / OUT_D &&
                dd <  g::START0 + ((k + 1) * g::L + OUT_D - 1) / OUT_D) {
                acc0[k - kg::K0] += v0;
                acc1[k - kg::K0] += v1;
            }
        }
    }

#pragma unroll
    for (int k = kg::K0; k < kg::K1; ++k) {
        const int   s  = (k * g::L) / OUT_D;
        const int   e  = ((k + 1) * g::L + OUT_D - 1) / OUT_D;
        const float wt = 1.0f / (float)(e - s);
        out0[(size_t)k * HW_] = acc0[k - kg::K0] * wt;
        out1[(size_t)k * HW_] = acc1[k - kg::K0] * wt;
    }
}

template<int AD, int WID>
__device__ __forceinline__ void run_pipe(
    const float* __restrict__ uh, const float* __restrict__ vw,
    float* __restrict__ out, float* buf0, float* buf1,
    int b0, int a, int h, int lane)
{
    float4 r[ST<AD, WID>::K];

    const size_t pl0      = (size_t)(b0 * A_ + a) * D_ * HW_ + (size_t)h * 64;
    const size_t pstride  = (size_t)A_ * D_ * HW_;                 // b -> b+1 (input)
    const size_t ob0      = ((size_t)(b0 * 2) * A_ + a) * OUT_D * HW_
                          + (size_t)h * 64 + (size_t)lane;          // n=0 base
    const size_t obstride = (size_t)2 * A_ * OUT_D * HW_;           // b -> b+1 (output)
    const size_t o01      = (size_t)A_ * OUT_D * HW_;               // n=0 -> n=1

    // prologue: stage tile 0
    stage_load<AD, WID>(vw + pl0, r, lane);
    stage_write<AD, WID>(buf0, r, lane);

    // step 0
    __syncthreads();
    stage_load<AD, WID>(vw + pl0 + pstride, r, lane);
    compute_tile<AD, WID>(uh + pl0, buf0,
                          out + ob0, out + ob0 + o01, h, lane);
    stage_write<AD, WID>(buf1, r, lane);

    // step 1
    __syncthreads();
    stage_load<AD, WID>(vw + pl0 + 2 * pstride, r, lane);
    compute_tile<AD, WID>(uh + pl0 + pstride, buf1,
                          out + ob0 + obstride, out + ob0 + obstride + o01, h, lane);
    stage_write<AD, WID>(buf0, r, lane);

    // step 2
    __syncthreads();
    stage_load<AD, WID>(vw + pl0 + 3 * pstride, r, lane);
    compute_tile<AD, WID>(uh + pl0 + 2 * pstride, buf0,
                          out + ob0 + 2 * obstride, out + ob0 + 2 * obstride + o01, h, lane);
    stage_write<AD, WID>(buf1, r, lane);

    // step 3
    __syncthreads();
    compute_tile<AD, WID>(uh + pl0 + 3 * pstride, buf1,
                          out + ob0 + 3 * obstride, out + ob0 + 3 * obstride + o01, h, lane);
}

template<int AD>
__device__ __forceinline__ void run_ad(
    const float* __restrict__ uh, const float* __restrict__ vw,
    float* __restrict__ out, float* buf0, float* buf1,
    int b0, int a, int h, int lane, int wid)
{
    switch (wid) {
        case 0: run_pipe<AD, 0>(uh, vw, out, buf0, buf1, b0, a, h, lane); break;
        case 1: run_pipe<AD, 1>(uh, vw, out, buf0, buf1, b0, a, h, lane); break;
        case 2: run_pipe<AD, 2>(uh, vw, out, buf0, buf1, b0, a, h, lane); break;
        case 3: run_pipe<AD, 3>(uh, vw, out, buf0, buf1, b0, a, h, lane); break;
        case 4: run_pipe<AD, 4>(uh, vw, out, buf0, buf1, b0, a, h, lane); break;
        case 5: run_pipe<AD, 5>(uh, vw, out, buf0, buf1, b0, a, h, lane); break;
        case 6: run_pipe<AD, 6>(uh, vw, out, buf0, buf1, b0, a, h, lane); break;
        default: run_pipe<AD, 7>(uh, vw, out, buf0, buf1, b0, a, h, lane); break;
    }
}

__global__ __launch_bounds__(512, 4) void cost_volume_kernel(
    const float* __restrict__ uh,
    const float* __restrict__ vw,
    float* __restrict__ out)
{
    __shared__ float buf0[D_ * 64];   // 32 KiB
    __shared__ float buf1[D_ * 64];   // 32 KiB

    const int h  = blockIdx.x;
    const int a  = blockIdx.y;
    const int b0 = (int)blockIdx.z * NT;
    const int t  = (int)threadIdx.x;
    const int lane = t & 63;
    const int wid  = t >> 6;

    switch (a) {
        case 3: case 4: case 5:
            run_ad<1>(uh, vw, out, buf0, buf1, b0, a, h, lane, wid); break;
        case 2: case 6:
            run_ad<2>(uh, vw, out, buf0, buf1, b0, a, h, lane, wid); break;
        case 1: case 7:
            run_ad<3>(uh, vw, out, buf0, buf1, b0, a, h, lane, wid); break;
        default:   // 0, 8
            run_ad<4>(uh, vw, out, buf0, buf1, b0, a, h, lane, wid); break;
    }
}

extern "C" void kernel_launch(void* const* d_in, const int* in_sizes, int n_in,
                              void* d_out, int out_size, void* d_ws, size_t ws_size,
                              hipStream_t stream) {
    const float* uh = (const float*)d_in[0];   // [8,9,128,64,64] f32
    const float* vw = (const float*)d_in[1];   // [8,9,128,64,64] f32
    float* out = (float*)d_out;                // [8,2,9,21,64,64] f32

    dim3 grid(64, A_, B_ / NT);   // (h, a, b-quad) = 1152 blocks
    dim3 block(512);
    cost_volume_kernel<<<grid, block, 0, stream>>>(uh, vw, out);
}